// Round 9
// baseline (9398.557 us; speedup 1.0000x reference)
//
#include <hip/hip_runtime.h>
#include <math.h>

#define NB 32              // batches per 512-thread block
#define SLAB_F 4096        // slab = 2 W-rows x 2048 floats = 16 KB
#define NSLAB 64           // 128 k-rows / 2 per slab
#define UNI_F 10240        // union: max(2*SLAB_F=8192, 8 waves*2*32*20=10240) floats

// R9 = R7 (verified 216us: full-wave gather, 64x2-row slabs, dbuf,
// __syncthreads drain) + ONE change: the per-iter sorted-list walk
// (serial ds_read chain ~120cy/gather + 48K cy/CU LDS ops) is replaced by
// per-wave 128-bit occupancy masks in SGPRs (__ballot), consumed 2 bits
// per slab via SALU rolling shift; gather guards are wave-uniform
// s_cbranch. R8's counted-vmcnt 1-row pipeline is REVERTED (375us: 128
// rendezvous with ~50cy bodies can't cover staging latency).
//  - gather: lane=(row 0..31, half 0..1) owns 8 floats; 2 full-activity
//    ds_read_b128 per occupied k (data floor: 2KB @128B/cy = 16cy; the
//    8-way quad serialization PMC-counts as conflicts - ignore).
//  - conflict-free chunk-parity rotation cc = c ^ (row&1).
//  - LU transpose via per-wave scratch aliased over dead slab bufs;
//    8-lane implicit-partial-pivot LU unchanged. k-sum ascending ->
//    bitwise-identical results.

typedef float f32x2 __attribute__((ext_vector_type(2)));
typedef float f32x4 __attribute__((ext_vector_type(4)));

#define GLD_LDS16(gp, lp) __builtin_amdgcn_global_load_lds( \
    (const __attribute__((address_space(1))) void*)(gp),    \
    (__attribute__((address_space(3))) void*)(lp), 16, 0, 0)

// acc (f32x2) += half of a b128 load, one packed add (IEEE-identical)
#define PKADD(acc, half) asm("v_pk_add_f32 %0, %0, %1" : "+v"(acc) : "v"(half))

__global__ __launch_bounds__(512, 4) void backflow_kernel(
    const int* __restrict__ nocc,   // (B,128) int32 0/1
    const float* __restrict__ W,    // (128,2048) f32 row-major
    float* __restrict__ out,        // planar: [B re][B im]
    int B)
{
    __shared__ __align__(16) float uni[UNI_F];   // slab dbuf, later scratch
    __shared__ int lists[NB][33];

    const int tid = threadIdx.x;

    // ---------------- phase 1: occupancy -> row lists (gather offsets) ------
    {
        const int bib1 = tid >> 4;                 // 0..31
        const int l16  = tid & 15;
        int batch1 = blockIdx.x * NB + bib1;
        if (batch1 >= B) batch1 = B - 1;
        const int4* np = reinterpret_cast<const int4*>(nocc + (size_t)batch1 * 128 + l16 * 8);
        int4 v0 = np[0];
        int4 v1 = np[1];
        unsigned nib = 0;
        nib |= (v0.x != 0) ? 1u   : 0u;
        nib |= (v0.y != 0) ? 2u   : 0u;
        nib |= (v0.z != 0) ? 4u   : 0u;
        nib |= (v0.w != 0) ? 8u   : 0u;
        nib |= (v1.x != 0) ? 16u  : 0u;
        nib |= (v1.y != 0) ? 32u  : 0u;
        nib |= (v1.z != 0) ? 64u  : 0u;
        nib |= (v1.w != 0) ? 128u : 0u;
        const int cnt = __popc(nib);
        int incl = cnt;
        const int seg = l16 & 7;
        #pragma unroll
        for (int d = 1; d < 8; d <<= 1) {
            int t = __shfl_up(incl, d, 8);
            if (seg >= d) incl += t;
        }
        int pos = ((l16 >> 3) << 4) + (incl - cnt);
        const int k0 = l16 * 8;
        #pragma unroll
        for (int b = 0; b < 8; b++) {
            if (nib & (1u << b)) lists[bib1][pos++] = k0 + b;
        }
    }
    __syncthreads();

    // ---------------- ids ----------------
    const int lane = tid & 63;
    const int wv   = __builtin_amdgcn_readfirstlane(tid >> 6);  // 0..7
    const int wb0  = wv << 2;            // first batch-in-wave

    const int rowidx = lane >> 1;        // owned A-row 0..31
    const int h      = lane & 1;         // 8-float half of the 16-col row
    const int m2     = rowidx >> 4;      // spin of owned row
    const int rot    = rowidx & 1;       // chunk-parity rotation key

    // ---------------- per-wave occupancy masks (SGPR via ballot) -----------
    unsigned long long mlo[4], mhi[4];
    #pragma unroll
    for (int b = 0; b < 4; b++) {
        int gb = blockIdx.x * NB + wb0 + b;
        if (gb >= B) gb = B - 1;
        const int* npb = nocc + (size_t)gb * 128;
        const int vlo = npb[lane];
        const int vhi = npb[64 + lane];
        mlo[b] = __ballot(vlo != 0);     // bit k   (k<64)
        mhi[b] = __ballot(vhi != 0);     // bit k-64
    }

    // ---------------- staging setup (linear) ----------------
    const int col_l = (wv << 8) + (lane << 2);
    const char* gp0 = (const char*)(W + col_l);
    const char* gp1 = (const char*)(W + 2048 + col_l);
    char* const lb_base = (char*)uni + (wv << 10);

    GLD_LDS16(gp0, lb_base);            // prologue: slab 0 -> buffer 0
    GLD_LDS16(gp1, lb_base + 8192);
    gp0 += 16384; gp1 += 16384;

    // per-batch row offsets (bytes within one staged k-row)
    int offs[4][2];
    #pragma unroll
    for (int b = 0; b < 4; b++) {
        const int ro = lists[wb0 + b][rowidx] - (m2 << 6);   // 0..63
        offs[b][0] = (ro << 7) + (m2 << 6) + (h << 5) + ((0 ^ rot) << 4);
        offs[b][1] = (ro << 7) + (m2 << 6) + (h << 5) + ((1 ^ rot) << 4);
    }

    f32x2 acc[4][4] = {};   // [batch][2*slot+e]; slot c = physical chunk c^rot

    __syncthreads();   // slab 0 resident (compiler drains vmcnt)

    // ---------------- main loop: stage next, gather current ----------------
    unsigned long long rm[4];
    #pragma unroll 1
    for (int half = 0; half < 2; half++) {
        #pragma unroll
        for (int b = 0; b < 4; b++) rm[b] = half ? mhi[b] : mlo[b];
        #pragma unroll 1
        for (int si = 0; si < 32; si++) {
            const int s = (half << 5) + si;
            if (s < NSLAB - 1) {
                char* lb = (char*)uni + (((s + 1) & 1) << 14) + (wv << 10);
                GLD_LDS16(gp0, lb);
                GLD_LDS16(gp1, lb + 8192);
                gp0 += 16384; gp1 += 16384;
            }
            const char* cpB = (const char*)uni + ((s & 1) << 14);
            #pragma unroll
            for (int b = 0; b < 4; b++) {
                if (rm[b] & 1ull) {                       // k = 2s (row 0)
                    const f32x4 v0 = *reinterpret_cast<const f32x4*>(cpB + offs[b][0]);
                    const f32x4 v1 = *reinterpret_cast<const f32x4*>(cpB + offs[b][1]);
                    PKADD(acc[b][0], v0.lo); PKADD(acc[b][1], v0.hi);
                    PKADD(acc[b][2], v1.lo); PKADD(acc[b][3], v1.hi);
                }
                if (rm[b] & 2ull) {                       // k = 2s+1 (row 1)
                    const f32x4 v0 = *reinterpret_cast<const f32x4*>(cpB + 8192 + offs[b][0]);
                    const f32x4 v1 = *reinterpret_cast<const f32x4*>(cpB + 8192 + offs[b][1]);
                    PKADD(acc[b][0], v0.lo); PKADD(acc[b][1], v0.hi);
                    PKADD(acc[b][2], v1.lo); PKADD(acc[b][3], v1.hi);
                }
                rm[b] >>= 2;
            }
            __syncthreads();
        }
    }
    // all gathers done -> bufs dead, safe to reuse as scratch

    // ---------------- within-wave transpose via per-wave scratch ----------
    const int g   = lane >> 3;          // LU group 0..7
    const int s8  = lane & 7;
    const int m   = g & 1;              // 0 = up, 1 = dn
    const int bwl = g >> 1;             // batch-in-wave 0..3
    int batch = blockIdx.x * NB + wb0 + bwl;
    const bool valid = (batch < B);
    if (!valid) batch = B - 1;

    float* const sw = uni + wv * 1280;          // [2 batches][32 rows][20]
    float* const wr = sw + rowidx * 20 + (h << 3);
    float a0[16], a1[16];

    // pass A: write batches 0,1; LU-read for lanes 0..31
    {
        f32x4 t;
        t.lo = acc[0][0]; t.hi = acc[0][1];
        *reinterpret_cast<f32x4*>(wr + ((0 ^ rot) << 2)) = t;
        t.lo = acc[0][2]; t.hi = acc[0][3];
        *reinterpret_cast<f32x4*>(wr + ((1 ^ rot) << 2)) = t;
        t.lo = acc[1][0]; t.hi = acc[1][1];
        *reinterpret_cast<f32x4*>(wr + 640 + ((0 ^ rot) << 2)) = t;
        t.lo = acc[1][2]; t.hi = acc[1][3];
        *reinterpret_cast<f32x4*>(wr + 640 + ((1 ^ rot) << 2)) = t;
    }
    asm volatile("s_waitcnt lgkmcnt(0)" ::: "memory");
    __builtin_amdgcn_sched_barrier(0);
    if (lane < 32) {
        const float* r0 = sw + bwl * 640 + (m * 16 + s8) * 20;
        const float* r1 = r0 + 160;
        #pragma unroll
        for (int qq = 0; qq < 4; qq++) {
            f32x4 u0 = *reinterpret_cast<const f32x4*>(r0 + qq * 4);
            f32x4 u1 = *reinterpret_cast<const f32x4*>(r1 + qq * 4);
            a0[qq*4+0] = u0.x; a0[qq*4+1] = u0.y; a0[qq*4+2] = u0.z; a0[qq*4+3] = u0.w;
            a1[qq*4+0] = u1.x; a1[qq*4+1] = u1.y; a1[qq*4+2] = u1.z; a1[qq*4+3] = u1.w;
        }
    }
    asm volatile("s_waitcnt lgkmcnt(0)" ::: "memory");
    __builtin_amdgcn_sched_barrier(0);
    // pass B: overwrite with batches 2,3; LU-read for lanes 32..63
    {
        f32x4 t;
        t.lo = acc[2][0]; t.hi = acc[2][1];
        *reinterpret_cast<f32x4*>(wr + ((0 ^ rot) << 2)) = t;
        t.lo = acc[2][2]; t.hi = acc[2][3];
        *reinterpret_cast<f32x4*>(wr + ((1 ^ rot) << 2)) = t;
        t.lo = acc[3][0]; t.hi = acc[3][1];
        *reinterpret_cast<f32x4*>(wr + 640 + ((0 ^ rot) << 2)) = t;
        t.lo = acc[3][2]; t.hi = acc[3][3];
        *reinterpret_cast<f32x4*>(wr + 640 + ((1 ^ rot) << 2)) = t;
    }
    asm volatile("s_waitcnt lgkmcnt(0)" ::: "memory");
    __builtin_amdgcn_sched_barrier(0);
    if (lane >= 32) {
        const float* r0 = sw + (bwl - 2) * 640 + (m * 16 + s8) * 20;
        const float* r1 = r0 + 160;
        #pragma unroll
        for (int qq = 0; qq < 4; qq++) {
            f32x4 u0 = *reinterpret_cast<const f32x4*>(r0 + qq * 4);
            f32x4 u1 = *reinterpret_cast<const f32x4*>(r1 + qq * 4);
            a0[qq*4+0] = u0.x; a0[qq*4+1] = u0.y; a0[qq*4+2] = u0.z; a0[qq*4+3] = u0.w;
            a1[qq*4+0] = u1.x; a1[qq*4+1] = u1.y; a1[qq*4+2] = u1.z; a1[qq*4+3] = u1.w;
        }
    }

    // ---------------- LU, implicit partial pivoting (register rows) --------
    unsigned active = 0xffffu;
    int inv = 0;
    float myd0 = 1.f, myd1 = 1.f;

    #pragma unroll
    for (int k = 0; k < 16; k++) {
        const unsigned act0 = (active >> s8) & 1u;
        const unsigned act1 = (active >> (s8 + 8)) & 1u;
        float av = act0 ? fabsf(a0[k]) : -1.f;
        int idx = s8;
        {
            float av1 = act1 ? fabsf(a1[k]) : -1.f;
            if (av1 > av) { av = av1; idx = s8 + 8; }
        }
        #pragma unroll
        for (int d = 1; d < 8; d <<= 1) {
            float ov = __shfl_xor(av, d, 8);
            int   oi = __shfl_xor(idx, d, 8);
            if (ov > av || (ov == av && oi < idx)) { av = ov; idx = oi; }
        }
        const int p = idx;
        const int plane = p & 7;
        const bool phi = (p & 8) != 0;
        float psel = phi ? a1[k] : a0[k];
        const float pk = __shfl(psel, plane, 8);
        const float rcp = 1.0f / pk;

        if (s8 == p)     myd0 = pk;
        if (s8 + 8 == p) myd1 = pk;
        inv += __popc(active & ((1u << p) - 1u));
        active &= ~(1u << p);

        const float f0 = (act0 && s8 != p)       ? a0[k] * rcp : 0.f;
        const float f1 = (act1 && (s8 + 8) != p) ? a1[k] * rcp : 0.f;

        #pragma unroll
        for (int j = k + 1; j < 16; j++) {
            float sel = phi ? a1[j] : a0[j];
            float pv = __shfl(sel, plane, 8);
            a0[j] = fmaf(-f0, pv, a0[j]);
            a1[j] = fmaf(-f1, pv, a1[j]);
        }
    }

    float ld = logf(fabsf(myd0)) + logf(fabsf(myd1));
    int ng = ((myd0 < 0.f) ? 1 : 0) + ((myd1 < 0.f) ? 1 : 0);
    #pragma unroll
    for (int d = 1; d < 8; d <<= 1) {
        ld += __shfl_xor(ld, d, 8);
        ng += __shfl_xor(ng, d, 8);
    }
    const int neg = (ng + inv) & 1;

    const float ld_o  = __shfl_xor(ld, 8, 16);
    const int   neg_o = __shfl_xor(neg, 8, 16);

    if ((lane & 15) == 0 && valid) {
        out[batch]     = ld + ld_o;                                      // re plane
        out[B + batch] = 3.14159265358979323846f * (float)(neg + neg_o); // im plane
    }
}

extern "C" void kernel_launch(void* const* d_in, const int* in_sizes, int n_in,
                              void* d_out, int out_size, void* d_ws, size_t ws_size,
                              hipStream_t stream) {
    const int* nocc = (const int*)d_in[0];
    const float* W  = (const float*)d_in[1];
    float* out = (float*)d_out;
    const int B = in_sizes[0] / 128;                 // 65536
    const int blocks = (B + NB - 1) / NB;            // 2048
    backflow_kernel<<<blocks, 512, 0, stream>>>(nocc, W, out, B);
}

// Round 10
// 248.406 us; speedup vs baseline: 37.8354x; 37.8354x over previous
//
#include <hip/hip_runtime.h>
#include <math.h>

#define NB 32              // batches per 512-thread block
#define SLAB_F 4096        // slab = 2 W-rows x 2048 floats = 16 KB
#define NSLAB 64           // 128 k-rows / 2 per slab
#define UNI_F 10240        // union: max(2*SLAB_F=8192, 8 waves*2*32*20=10240) floats

// R10 = R7 (verified 216us) + SGPR occupancy masks, spill-safe this time.
// R9's 45 GB WRITE_SIZE post-mortem: ballot masks stayed in VGPRs ->
// guards if-converted (exec predication, not s_cbranch) -> 8 gather bodies
// straight-lined -> 16 live f32x4 temps -> acc spilled to scratch.
// Fix: force masks to SGPR via readfirstlane of both 32-bit halves (proven
// wave-uniform -> s_cbranch -> bodies in separate basic blocks -> no
// hoisting). Named scalars r0..r3, no arrays (rule #20).
//  - gather: full-wave, lane=(row 0..31, half h) owns 8 floats; 2
//    full-activity ds_read_b128 per occupied k (the 2KB/128B = 16cy floor;
//    8-way quad serialization PMC-counts as conflict - ignore).
//  - conflict-free chunk-parity rotation cc = c ^ (row&1).
//  - 64x 2-row slabs, double-buffered global_load_lds, __syncthreads drain
//    (R8 falsified finer pipelining).
//  - LU transpose via per-wave scratch aliased over dead slab bufs; 8-lane
//    implicit-partial-pivot LU. k-sum ascending -> bitwise-identical.

typedef float f32x2 __attribute__((ext_vector_type(2)));
typedef float f32x4 __attribute__((ext_vector_type(4)));

#define GLD_LDS16(gp, lp) __builtin_amdgcn_global_load_lds( \
    (const __attribute__((address_space(1))) void*)(gp),    \
    (__attribute__((address_space(3))) void*)(lp), 16, 0, 0)

// acc (f32x2) += half of a b128 load, one packed add (IEEE-identical)
#define PKADD(acc, half) asm("v_pk_add_f32 %0, %0, %1" : "+v"(acc) : "v"(half))

// force a wave-uniform u64 into SGPRs (and prove uniformity to the compiler)
__device__ __forceinline__ unsigned long long uniform_u64(unsigned long long x) {
    unsigned lo = __builtin_amdgcn_readfirstlane((unsigned)x);
    unsigned hi = __builtin_amdgcn_readfirstlane((unsigned)(x >> 32));
    return ((unsigned long long)hi << 32) | lo;
}

__global__ __launch_bounds__(512, 4) void backflow_kernel(
    const int* __restrict__ nocc,   // (B,128) int32 0/1
    const float* __restrict__ W,    // (128,2048) f32 row-major
    float* __restrict__ out,        // planar: [B re][B im]
    int B)
{
    __shared__ __align__(16) float uni[UNI_F];   // slab dbuf, later scratch
    __shared__ int lists[NB][33];

    const int tid = threadIdx.x;

    // ---------------- phase 1: occupancy -> row lists (gather offsets) ------
    {
        const int bib1 = tid >> 4;                 // 0..31
        const int l16  = tid & 15;
        int batch1 = blockIdx.x * NB + bib1;
        if (batch1 >= B) batch1 = B - 1;
        const int4* np = reinterpret_cast<const int4*>(nocc + (size_t)batch1 * 128 + l16 * 8);
        int4 v0 = np[0];
        int4 v1 = np[1];
        unsigned nib = 0;
        nib |= (v0.x != 0) ? 1u   : 0u;
        nib |= (v0.y != 0) ? 2u   : 0u;
        nib |= (v0.z != 0) ? 4u   : 0u;
        nib |= (v0.w != 0) ? 8u   : 0u;
        nib |= (v1.x != 0) ? 16u  : 0u;
        nib |= (v1.y != 0) ? 32u  : 0u;
        nib |= (v1.z != 0) ? 64u  : 0u;
        nib |= (v1.w != 0) ? 128u : 0u;
        const int cnt = __popc(nib);
        int incl = cnt;
        const int seg = l16 & 7;
        #pragma unroll
        for (int d = 1; d < 8; d <<= 1) {
            int t = __shfl_up(incl, d, 8);
            if (seg >= d) incl += t;
        }
        int pos = ((l16 >> 3) << 4) + (incl - cnt);
        const int k0 = l16 * 8;
        #pragma unroll
        for (int b = 0; b < 8; b++) {
            if (nib & (1u << b)) lists[bib1][pos++] = k0 + b;
        }
    }
    __syncthreads();

    // ---------------- ids ----------------
    const int lane = tid & 63;
    const int wv   = __builtin_amdgcn_readfirstlane(tid >> 6);  // 0..7
    const int wb0  = wv << 2;            // first batch-in-wave

    const int rowidx = lane >> 1;        // owned A-row 0..31
    const int h      = lane & 1;         // 8-float half of the 16-col row
    const int m2     = rowidx >> 4;      // spin of owned row
    const int rot    = rowidx & 1;       // chunk-parity rotation key

    // ---------------- per-wave occupancy masks -> SGPRs ----------------
    unsigned long long b0lo, b0hi, b1lo, b1hi, b2lo, b2hi, b3lo, b3hi;
    {
        const size_t base = (size_t)blockIdx.x * NB + wb0;
        int g0 = (int)base + 0, g1 = (int)base + 1, g2 = (int)base + 2, g3 = (int)base + 3;
        if (g0 >= B) g0 = B - 1;
        if (g1 >= B) g1 = B - 1;
        if (g2 >= B) g2 = B - 1;
        if (g3 >= B) g3 = B - 1;
        const int* p0 = nocc + (size_t)g0 * 128;
        const int* p1 = nocc + (size_t)g1 * 128;
        const int* p2 = nocc + (size_t)g2 * 128;
        const int* p3 = nocc + (size_t)g3 * 128;
        b0lo = uniform_u64(__ballot(p0[lane] != 0));
        b0hi = uniform_u64(__ballot(p0[64 + lane] != 0));
        b1lo = uniform_u64(__ballot(p1[lane] != 0));
        b1hi = uniform_u64(__ballot(p1[64 + lane] != 0));
        b2lo = uniform_u64(__ballot(p2[lane] != 0));
        b2hi = uniform_u64(__ballot(p2[64 + lane] != 0));
        b3lo = uniform_u64(__ballot(p3[lane] != 0));
        b3hi = uniform_u64(__ballot(p3[64 + lane] != 0));
    }

    // ---------------- staging setup (linear) ----------------
    const int col_l = (wv << 8) + (lane << 2);
    const char* gp0 = (const char*)(W + col_l);
    const char* gp1 = (const char*)(W + 2048 + col_l);
    char* const lb_base = (char*)uni + (wv << 10);

    GLD_LDS16(gp0, lb_base);            // prologue: slab 0 -> buffer 0
    GLD_LDS16(gp1, lb_base + 8192);
    gp0 += 16384; gp1 += 16384;

    // per-batch row offsets (bytes within one staged k-row)
    int off00, off01, off10, off11, off20, off21, off30, off31;
    {
        const int r0 = lists[wb0 + 0][rowidx] - (m2 << 6);
        const int r1 = lists[wb0 + 1][rowidx] - (m2 << 6);
        const int r2 = lists[wb0 + 2][rowidx] - (m2 << 6);
        const int r3 = lists[wb0 + 3][rowidx] - (m2 << 6);
        const int cbase = (m2 << 6) + (h << 5);
        off00 = (r0 << 7) + cbase + ((0 ^ rot) << 4);
        off01 = (r0 << 7) + cbase + ((1 ^ rot) << 4);
        off10 = (r1 << 7) + cbase + ((0 ^ rot) << 4);
        off11 = (r1 << 7) + cbase + ((1 ^ rot) << 4);
        off20 = (r2 << 7) + cbase + ((0 ^ rot) << 4);
        off21 = (r2 << 7) + cbase + ((1 ^ rot) << 4);
        off30 = (r3 << 7) + cbase + ((0 ^ rot) << 4);
        off31 = (r3 << 7) + cbase + ((1 ^ rot) << 4);
    }

    f32x2 acc[4][4] = {};   // [batch][2*slot+e]; slot c = physical chunk c^rot

    __syncthreads();   // slab 0 resident (compiler drains vmcnt)

    // ---------------- main loop: stage next, gather current ----------------
    // gather body for one (batch, k-row): oA/oB are this batch's two chunk
    // offsets, kb is the byte base of the k-row inside the current buffer.
    #define GBODY(bb, oA, oB, kb)                                              \
        {                                                                      \
            const f32x4 v0 = *reinterpret_cast<const f32x4*>((kb) + (oA));     \
            const f32x4 v1 = *reinterpret_cast<const f32x4*>((kb) + (oB));     \
            PKADD(acc[bb][0], v0.lo); PKADD(acc[bb][1], v0.hi);                \
            PKADD(acc[bb][2], v1.lo); PKADD(acc[bb][3], v1.hi);                \
        }

    unsigned long long r0 = b0lo, r1 = b1lo, r2 = b2lo, r3 = b3lo;
    #pragma unroll 1
    for (int s = 0; s < NSLAB; s++) {
        if (s == 32) { r0 = b0hi; r1 = b1hi; r2 = b2hi; r3 = b3hi; }
        if (s < NSLAB - 1) {
            char* lb = (char*)uni + (((s + 1) & 1) << 14) + (wv << 10);
            GLD_LDS16(gp0, lb);
            GLD_LDS16(gp1, lb + 8192);
            gp0 += 16384; gp1 += 16384;
        }
        const char* cpB = (const char*)uni + ((s & 1) << 14);
        if (r0 & 1ull) GBODY(0, off00, off01, cpB)
        if (r0 & 2ull) GBODY(0, off00, off01, cpB + 8192)
        if (r1 & 1ull) GBODY(1, off10, off11, cpB)
        if (r1 & 2ull) GBODY(1, off10, off11, cpB + 8192)
        if (r2 & 1ull) GBODY(2, off20, off21, cpB)
        if (r2 & 2ull) GBODY(2, off20, off21, cpB + 8192)
        if (r3 & 1ull) GBODY(3, off30, off31, cpB)
        if (r3 & 2ull) GBODY(3, off30, off31, cpB + 8192)
        r0 >>= 2; r1 >>= 2; r2 >>= 2; r3 >>= 2;
        __syncthreads();
    }
    // all gathers done -> bufs dead, safe to reuse as scratch

    // ---------------- within-wave transpose via per-wave scratch ----------
    const int g   = lane >> 3;          // LU group 0..7
    const int s8  = lane & 7;
    const int m   = g & 1;              // 0 = up, 1 = dn
    const int bwl = g >> 1;             // batch-in-wave 0..3
    int batch = blockIdx.x * NB + wb0 + bwl;
    const bool valid = (batch < B);
    if (!valid) batch = B - 1;

    float* const sw = uni + wv * 1280;          // [2 batches][32 rows][20]
    float* const wr = sw + rowidx * 20 + (h << 3);
    float a0[16], a1[16];

    // pass A: write batches 0,1; LU-read for lanes 0..31
    {
        f32x4 t;
        t.lo = acc[0][0]; t.hi = acc[0][1];
        *reinterpret_cast<f32x4*>(wr + ((0 ^ rot) << 2)) = t;
        t.lo = acc[0][2]; t.hi = acc[0][3];
        *reinterpret_cast<f32x4*>(wr + ((1 ^ rot) << 2)) = t;
        t.lo = acc[1][0]; t.hi = acc[1][1];
        *reinterpret_cast<f32x4*>(wr + 640 + ((0 ^ rot) << 2)) = t;
        t.lo = acc[1][2]; t.hi = acc[1][3];
        *reinterpret_cast<f32x4*>(wr + 640 + ((1 ^ rot) << 2)) = t;
    }
    asm volatile("s_waitcnt lgkmcnt(0)" ::: "memory");
    __builtin_amdgcn_sched_barrier(0);
    if (lane < 32) {
        const float* rr0 = sw + bwl * 640 + (m * 16 + s8) * 20;
        const float* rr1 = rr0 + 160;
        #pragma unroll
        for (int qq = 0; qq < 4; qq++) {
            f32x4 u0 = *reinterpret_cast<const f32x4*>(rr0 + qq * 4);
            f32x4 u1 = *reinterpret_cast<const f32x4*>(rr1 + qq * 4);
            a0[qq*4+0] = u0.x; a0[qq*4+1] = u0.y; a0[qq*4+2] = u0.z; a0[qq*4+3] = u0.w;
            a1[qq*4+0] = u1.x; a1[qq*4+1] = u1.y; a1[qq*4+2] = u1.z; a1[qq*4+3] = u1.w;
        }
    }
    asm volatile("s_waitcnt lgkmcnt(0)" ::: "memory");
    __builtin_amdgcn_sched_barrier(0);
    // pass B: overwrite with batches 2,3; LU-read for lanes 32..63
    {
        f32x4 t;
        t.lo = acc[2][0]; t.hi = acc[2][1];
        *reinterpret_cast<f32x4*>(wr + ((0 ^ rot) << 2)) = t;
        t.lo = acc[2][2]; t.hi = acc[2][3];
        *reinterpret_cast<f32x4*>(wr + ((1 ^ rot) << 2)) = t;
        t.lo = acc[3][0]; t.hi = acc[3][1];
        *reinterpret_cast<f32x4*>(wr + 640 + ((0 ^ rot) << 2)) = t;
        t.lo = acc[3][2]; t.hi = acc[3][3];
        *reinterpret_cast<f32x4*>(wr + 640 + ((1 ^ rot) << 2)) = t;
    }
    asm volatile("s_waitcnt lgkmcnt(0)" ::: "memory");
    __builtin_amdgcn_sched_barrier(0);
    if (lane >= 32) {
        const float* rr0 = sw + (bwl - 2) * 640 + (m * 16 + s8) * 20;
        const float* rr1 = rr0 + 160;
        #pragma unroll
        for (int qq = 0; qq < 4; qq++) {
            f32x4 u0 = *reinterpret_cast<const f32x4*>(rr0 + qq * 4);
            f32x4 u1 = *reinterpret_cast<const f32x4*>(rr1 + qq * 4);
            a0[qq*4+0] = u0.x; a0[qq*4+1] = u0.y; a0[qq*4+2] = u0.z; a0[qq*4+3] = u0.w;
            a1[qq*4+0] = u1.x; a1[qq*4+1] = u1.y; a1[qq*4+2] = u1.z; a1[qq*4+3] = u1.w;
        }
    }

    // ---------------- LU, implicit partial pivoting (register rows) --------
    unsigned active = 0xffffu;
    int inv = 0;
    float myd0 = 1.f, myd1 = 1.f;

    #pragma unroll
    for (int k = 0; k < 16; k++) {
        const unsigned act0 = (active >> s8) & 1u;
        const unsigned act1 = (active >> (s8 + 8)) & 1u;
        float av = act0 ? fabsf(a0[k]) : -1.f;
        int idx = s8;
        {
            float av1 = act1 ? fabsf(a1[k]) : -1.f;
            if (av1 > av) { av = av1; idx = s8 + 8; }
        }
        #pragma unroll
        for (int d = 1; d < 8; d <<= 1) {
            float ov = __shfl_xor(av, d, 8);
            int   oi = __shfl_xor(idx, d, 8);
            if (ov > av || (ov == av && oi < idx)) { av = ov; idx = oi; }
        }
        const int p = idx;
        const int plane = p & 7;
        const bool phi = (p & 8) != 0;
        float psel = phi ? a1[k] : a0[k];
        const float pk = __shfl(psel, plane, 8);
        const float rcp = 1.0f / pk;

        if (s8 == p)     myd0 = pk;
        if (s8 + 8 == p) myd1 = pk;
        inv += __popc(active & ((1u << p) - 1u));
        active &= ~(1u << p);

        const float f0 = (act0 && s8 != p)       ? a0[k] * rcp : 0.f;
        const float f1 = (act1 && (s8 + 8) != p) ? a1[k] * rcp : 0.f;

        #pragma unroll
        for (int j = k + 1; j < 16; j++) {
            float sel = phi ? a1[j] : a0[j];
            float pv = __shfl(sel, plane, 8);
            a0[j] = fmaf(-f0, pv, a0[j]);
            a1[j] = fmaf(-f1, pv, a1[j]);
        }
    }

    float ld = logf(fabsf(myd0)) + logf(fabsf(myd1));
    int ng = ((myd0 < 0.f) ? 1 : 0) + ((myd1 < 0.f) ? 1 : 0);
    #pragma unroll
    for (int d = 1; d < 8; d <<= 1) {
        ld += __shfl_xor(ld, d, 8);
        ng += __shfl_xor(ng, d, 8);
    }
    const int neg = (ng + inv) & 1;

    const float ld_o  = __shfl_xor(ld, 8, 16);
    const int   neg_o = __shfl_xor(neg, 8, 16);

    if ((lane & 15) == 0 && valid) {
        out[batch]     = ld + ld_o;                                      // re plane
        out[B + batch] = 3.14159265358979323846f * (float)(neg + neg_o); // im plane
    }
}

extern "C" void kernel_launch(void* const* d_in, const int* in_sizes, int n_in,
                              void* d_out, int out_size, void* d_ws, size_t ws_size,
                              hipStream_t stream) {
    const int* nocc = (const int*)d_in[0];
    const float* W  = (const float*)d_in[1];
    float* out = (float*)d_out;
    const int B = in_sizes[0] / 128;                 // 65536
    const int blocks = (B + NB - 1) / NB;            // 2048
    backflow_kernel<<<blocks, 512, 0, stream>>>(nocc, W, out, B);
}

// Round 11
// 239.789 us; speedup vs baseline: 39.1951x; 1.0359x over previous
//
#include <hip/hip_runtime.h>
#include <math.h>

#define NB 32              // batches per 512-thread block
#define SLAB_F 4096        // slab = 2 W-rows x 2048 floats = 16 KB
#define NSLAB 64           // 128 k-rows / 2 per slab
#define UNI_F 8192         // 32 KB: slab dbuf UNION transpose scratch (exact fit)

// R11 = R10 + occupancy 61->100%: LDS cut 45.5->36.2 KB (4 blocks/CU).
// R10 post-mortem: no pipe saturated (LDS 39%, VALU 33%), occupancy 61% ->
// rendezvous/latency idle is the wall; more co-resident blocks fill it.
// The scratch now EXACT-FITS the slab union: per wave 1024 f =
// [2 batches][32 rows][16 f], conflict-free via per-row chunk swizzle
// cs = q ^ ((row>>1)&3) resolved in write/read addresses:
//   write quads = 4*(row&1) + (2h+par)^((row>>1)&3) -> 8 lanes/quad exact;
//   read (32 lanes) -> 4 lanes/quad. No unrotation pass needed.
//  - gather: full-wave, lane=(row 0..31, half h); 2 full-activity
//    ds_read_b128 per occupied k; chunk-parity rotation c^rot (rot=row&1).
//  - occupancy masks in SGPRs via ballot+readfirstlane (R10, spill-safe).
//  - 64x 2-row slabs, dbuf global_load_lds, __syncthreads drain.
//  - LU: 8-lane implicit partial pivot. k-sum ascending -> bitwise-identical.

typedef float f32x2 __attribute__((ext_vector_type(2)));
typedef float f32x4 __attribute__((ext_vector_type(4)));

#define GLD_LDS16(gp, lp) __builtin_amdgcn_global_load_lds( \
    (const __attribute__((address_space(1))) void*)(gp),    \
    (__attribute__((address_space(3))) void*)(lp), 16, 0, 0)

// acc (f32x2) += half of a b128 load, one packed add (IEEE-identical)
#define PKADD(acc, half) asm("v_pk_add_f32 %0, %0, %1" : "+v"(acc) : "v"(half))

// force a wave-uniform u64 into SGPRs (prove uniformity to the compiler)
__device__ __forceinline__ unsigned long long uniform_u64(unsigned long long x) {
    unsigned lo = __builtin_amdgcn_readfirstlane((unsigned)x);
    unsigned hi = __builtin_amdgcn_readfirstlane((unsigned)(x >> 32));
    return ((unsigned long long)hi << 32) | lo;
}

__global__ __launch_bounds__(512, 8) void backflow_kernel(
    const int* __restrict__ nocc,   // (B,128) int32 0/1
    const float* __restrict__ W,    // (128,2048) f32 row-major
    float* __restrict__ out,        // planar: [B re][B im]
    int B)
{
    __shared__ __align__(16) float uni[UNI_F];   // slab dbuf / scratch union
    __shared__ int lists[NB][33];

    const int tid = threadIdx.x;

    // ---------------- phase 1: occupancy -> row lists (gather offsets) ------
    {
        const int bib1 = tid >> 4;                 // 0..31
        const int l16  = tid & 15;
        int batch1 = blockIdx.x * NB + bib1;
        if (batch1 >= B) batch1 = B - 1;
        const int4* np = reinterpret_cast<const int4*>(nocc + (size_t)batch1 * 128 + l16 * 8);
        int4 v0 = np[0];
        int4 v1 = np[1];
        unsigned nib = 0;
        nib |= (v0.x != 0) ? 1u   : 0u;
        nib |= (v0.y != 0) ? 2u   : 0u;
        nib |= (v0.z != 0) ? 4u   : 0u;
        nib |= (v0.w != 0) ? 8u   : 0u;
        nib |= (v1.x != 0) ? 16u  : 0u;
        nib |= (v1.y != 0) ? 32u  : 0u;
        nib |= (v1.z != 0) ? 64u  : 0u;
        nib |= (v1.w != 0) ? 128u : 0u;
        const int cnt = __popc(nib);
        int incl = cnt;
        const int seg = l16 & 7;
        #pragma unroll
        for (int d = 1; d < 8; d <<= 1) {
            int t = __shfl_up(incl, d, 8);
            if (seg >= d) incl += t;
        }
        int pos = ((l16 >> 3) << 4) + (incl - cnt);
        const int k0 = l16 * 8;
        #pragma unroll
        for (int b = 0; b < 8; b++) {
            if (nib & (1u << b)) lists[bib1][pos++] = k0 + b;
        }
    }
    __syncthreads();

    // ---------------- ids ----------------
    const int lane = tid & 63;
    const int wv   = __builtin_amdgcn_readfirstlane(tid >> 6);  // 0..7
    const int wb0  = wv << 2;            // first batch-in-wave

    const int rowidx = lane >> 1;        // owned A-row 0..31
    const int h      = lane & 1;         // 8-float half of the 16-col row
    const int m2     = rowidx >> 4;      // spin of owned row
    const int rot    = rowidx & 1;       // chunk-parity rotation key

    // ---------------- per-wave occupancy masks -> SGPRs ----------------
    unsigned long long b0lo, b0hi, b1lo, b1hi, b2lo, b2hi, b3lo, b3hi;
    {
        const size_t base = (size_t)blockIdx.x * NB + wb0;
        int g0 = (int)base + 0, g1 = (int)base + 1, g2 = (int)base + 2, g3 = (int)base + 3;
        if (g0 >= B) g0 = B - 1;
        if (g1 >= B) g1 = B - 1;
        if (g2 >= B) g2 = B - 1;
        if (g3 >= B) g3 = B - 1;
        const int* p0 = nocc + (size_t)g0 * 128;
        const int* p1 = nocc + (size_t)g1 * 128;
        const int* p2 = nocc + (size_t)g2 * 128;
        const int* p3 = nocc + (size_t)g3 * 128;
        b0lo = uniform_u64(__ballot(p0[lane] != 0));
        b0hi = uniform_u64(__ballot(p0[64 + lane] != 0));
        b1lo = uniform_u64(__ballot(p1[lane] != 0));
        b1hi = uniform_u64(__ballot(p1[64 + lane] != 0));
        b2lo = uniform_u64(__ballot(p2[lane] != 0));
        b2hi = uniform_u64(__ballot(p2[64 + lane] != 0));
        b3lo = uniform_u64(__ballot(p3[lane] != 0));
        b3hi = uniform_u64(__ballot(p3[64 + lane] != 0));
    }

    // ---------------- staging setup (linear) ----------------
    const int col_l = (wv << 8) + (lane << 2);
    const char* gp0 = (const char*)(W + col_l);
    const char* gp1 = (const char*)(W + 2048 + col_l);
    char* const lb_base = (char*)uni + (wv << 10);

    GLD_LDS16(gp0, lb_base);            // prologue: slab 0 -> buffer 0
    GLD_LDS16(gp1, lb_base + 8192);
    gp0 += 16384; gp1 += 16384;

    // per-batch row offsets (bytes within one staged k-row)
    int off00, off01, off10, off11, off20, off21, off30, off31;
    {
        const int r0 = lists[wb0 + 0][rowidx] - (m2 << 6);
        const int r1 = lists[wb0 + 1][rowidx] - (m2 << 6);
        const int r2 = lists[wb0 + 2][rowidx] - (m2 << 6);
        const int r3 = lists[wb0 + 3][rowidx] - (m2 << 6);
        const int cbase = (m2 << 6) + (h << 5);
        off00 = (r0 << 7) + cbase + ((0 ^ rot) << 4);
        off01 = (r0 << 7) + cbase + ((1 ^ rot) << 4);
        off10 = (r1 << 7) + cbase + ((0 ^ rot) << 4);
        off11 = (r1 << 7) + cbase + ((1 ^ rot) << 4);
        off20 = (r2 << 7) + cbase + ((0 ^ rot) << 4);
        off21 = (r2 << 7) + cbase + ((1 ^ rot) << 4);
        off30 = (r3 << 7) + cbase + ((0 ^ rot) << 4);
        off31 = (r3 << 7) + cbase + ((1 ^ rot) << 4);
    }

    f32x2 acc[4][4] = {};   // [batch][2*slot+e]; slots 0,1 = chunk q=2h+rot,
                            //                    slots 2,3 = chunk q=2h+1-rot

    __syncthreads();   // slab 0 resident (compiler drains vmcnt)

    // ---------------- main loop: stage next, gather current ----------------
    #define GBODY(bb, oA, oB, kb)                                              \
        {                                                                      \
            const f32x4 v0 = *reinterpret_cast<const f32x4*>((kb) + (oA));     \
            const f32x4 v1 = *reinterpret_cast<const f32x4*>((kb) + (oB));     \
            PKADD(acc[bb][0], v0.lo); PKADD(acc[bb][1], v0.hi);                \
            PKADD(acc[bb][2], v1.lo); PKADD(acc[bb][3], v1.hi);                \
        }

    unsigned long long r0m = b0lo, r1m = b1lo, r2m = b2lo, r3m = b3lo;
    #pragma unroll 1
    for (int s = 0; s < NSLAB; s++) {
        if (s == 32) { r0m = b0hi; r1m = b1hi; r2m = b2hi; r3m = b3hi; }
        if (s < NSLAB - 1) {
            char* lb = (char*)uni + (((s + 1) & 1) << 14) + (wv << 10);
            GLD_LDS16(gp0, lb);
            GLD_LDS16(gp1, lb + 8192);
            gp0 += 16384; gp1 += 16384;
        }
        const char* cpB = (const char*)uni + ((s & 1) << 14);
        if (r0m & 1ull) GBODY(0, off00, off01, cpB)
        if (r0m & 2ull) GBODY(0, off00, off01, cpB + 8192)
        if (r1m & 1ull) GBODY(1, off10, off11, cpB)
        if (r1m & 2ull) GBODY(1, off10, off11, cpB + 8192)
        if (r2m & 1ull) GBODY(2, off20, off21, cpB)
        if (r2m & 2ull) GBODY(2, off20, off21, cpB + 8192)
        if (r3m & 1ull) GBODY(3, off30, off31, cpB)
        if (r3m & 2ull) GBODY(3, off30, off31, cpB + 8192)
        r0m >>= 2; r1m >>= 2; r2m >>= 2; r3m >>= 2;
        __syncthreads();
    }
    // final barrier passed: all waves done gathering -> slab dead, reuse as scratch

    // ---------------- within-wave transpose via exact-fit swizzled scratch --
    const int g   = lane >> 3;          // LU group 0..7
    const int s8  = lane & 7;
    const int m   = g & 1;              // 0 = up, 1 = dn
    const int bwl = g >> 1;             // batch-in-wave 0..3
    int batch = blockIdx.x * NB + wb0 + bwl;
    const bool valid = (batch < B);
    if (!valid) batch = B - 1;

    // scratch: per wave 1024 f = [2 batches][32 rows][16]; chunk q of row r
    // stored at physical chunk q ^ ((r>>1)&3).
    float* const sw = uni + (wv << 10);
    const int wsw = (rowidx >> 1) & 3;
    const int q0 = (h << 1) + rot;          // logical chunk in acc slots 0,1
    const int q1 = (h << 1) + (1 - rot);    // logical chunk in acc slots 2,3
    float* const wr0 = sw + rowidx * 16 + ((q0 ^ wsw) << 2);
    float* const wr1 = sw + rowidx * 16 + ((q1 ^ wsw) << 2);
    float a0[16], a1[16];

    // pass A: write batches 0,1; LU-read for lanes 0..31
    {
        f32x4 t;
        t.lo = acc[0][0]; t.hi = acc[0][1]; *reinterpret_cast<f32x4*>(wr0) = t;
        t.lo = acc[0][2]; t.hi = acc[0][3]; *reinterpret_cast<f32x4*>(wr1) = t;
        t.lo = acc[1][0]; t.hi = acc[1][1]; *reinterpret_cast<f32x4*>(wr0 + 512) = t;
        t.lo = acc[1][2]; t.hi = acc[1][3]; *reinterpret_cast<f32x4*>(wr1 + 512) = t;
    }
    asm volatile("s_waitcnt lgkmcnt(0)" ::: "memory");
    __builtin_amdgcn_sched_barrier(0);
    if (lane < 32) {
        const float* rbase = sw + bwl * 512;
        const int ra = (m << 4) + s8;
        const int rb = ra + 8;
        const int va = (ra >> 1) & 3;       // == (rb>>1)&3
        #pragma unroll
        for (int q = 0; q < 4; q++) {
            f32x4 u0 = *reinterpret_cast<const f32x4*>(rbase + ra * 16 + ((q ^ va) << 2));
            f32x4 u1 = *reinterpret_cast<const f32x4*>(rbase + rb * 16 + ((q ^ va) << 2));
            a0[q*4+0] = u0.x; a0[q*4+1] = u0.y; a0[q*4+2] = u0.z; a0[q*4+3] = u0.w;
            a1[q*4+0] = u1.x; a1[q*4+1] = u1.y; a1[q*4+2] = u1.z; a1[q*4+3] = u1.w;
        }
    }
    asm volatile("s_waitcnt lgkmcnt(0)" ::: "memory");
    __builtin_amdgcn_sched_barrier(0);
    // pass B: overwrite with batches 2,3; LU-read for lanes 32..63
    {
        f32x4 t;
        t.lo = acc[2][0]; t.hi = acc[2][1]; *reinterpret_cast<f32x4*>(wr0) = t;
        t.lo = acc[2][2]; t.hi = acc[2][3]; *reinterpret_cast<f32x4*>(wr1) = t;
        t.lo = acc[3][0]; t.hi = acc[3][1]; *reinterpret_cast<f32x4*>(wr0 + 512) = t;
        t.lo = acc[3][2]; t.hi = acc[3][3]; *reinterpret_cast<f32x4*>(wr1 + 512) = t;
    }
    asm volatile("s_waitcnt lgkmcnt(0)" ::: "memory");
    __builtin_amdgcn_sched_barrier(0);
    if (lane >= 32) {
        const float* rbase = sw + (bwl - 2) * 512;
        const int ra = (m << 4) + s8;
        const int rb = ra + 8;
        const int va = (ra >> 1) & 3;
        #pragma unroll
        for (int q = 0; q < 4; q++) {
            f32x4 u0 = *reinterpret_cast<const f32x4*>(rbase + ra * 16 + ((q ^ va) << 2));
            f32x4 u1 = *reinterpret_cast<const f32x4*>(rbase + rb * 16 + ((q ^ va) << 2));
            a0[q*4+0] = u0.x; a0[q*4+1] = u0.y; a0[q*4+2] = u0.z; a0[q*4+3] = u0.w;
            a1[q*4+0] = u1.x; a1[q*4+1] = u1.y; a1[q*4+2] = u1.z; a1[q*4+3] = u1.w;
        }
    }

    // ---------------- LU, implicit partial pivoting (register rows) --------
    unsigned active = 0xffffu;
    int inv = 0;
    float myd0 = 1.f, myd1 = 1.f;

    #pragma unroll
    for (int k = 0; k < 16; k++) {
        const unsigned act0 = (active >> s8) & 1u;
        const unsigned act1 = (active >> (s8 + 8)) & 1u;
        float av = act0 ? fabsf(a0[k]) : -1.f;
        int idx = s8;
        {
            float av1 = act1 ? fabsf(a1[k]) : -1.f;
            if (av1 > av) { av = av1; idx = s8 + 8; }
        }
        #pragma unroll
        for (int d = 1; d < 8; d <<= 1) {
            float ov = __shfl_xor(av, d, 8);
            int   oi = __shfl_xor(idx, d, 8);
            if (ov > av || (ov == av && oi < idx)) { av = ov; idx = oi; }
        }
        const int p = idx;
        const int plane = p & 7;
        const bool phi = (p & 8) != 0;
        float psel = phi ? a1[k] : a0[k];
        const float pk = __shfl(psel, plane, 8);
        const float rcp = 1.0f / pk;

        if (s8 == p)     myd0 = pk;
        if (s8 + 8 == p) myd1 = pk;
        inv += __popc(active & ((1u << p) - 1u));
        active &= ~(1u << p);

        const float f0 = (act0 && s8 != p)       ? a0[k] * rcp : 0.f;
        const float f1 = (act1 && (s8 + 8) != p) ? a1[k] * rcp : 0.f;

        #pragma unroll
        for (int j = k + 1; j < 16; j++) {
            float sel = phi ? a1[j] : a0[j];
            float pv = __shfl(sel, plane, 8);
            a0[j] = fmaf(-f0, pv, a0[j]);
            a1[j] = fmaf(-f1, pv, a1[j]);
        }
    }

    float ld = logf(fabsf(myd0)) + logf(fabsf(myd1));
    int ng = ((myd0 < 0.f) ? 1 : 0) + ((myd1 < 0.f) ? 1 : 0);
    #pragma unroll
    for (int d = 1; d < 8; d <<= 1) {
        ld += __shfl_xor(ld, d, 8);
        ng += __shfl_xor(ng, d, 8);
    }
    const int neg = (ng + inv) & 1;

    const float ld_o  = __shfl_xor(ld, 8, 16);
    const int   neg_o = __shfl_xor(neg, 8, 16);

    if ((lane & 15) == 0 && valid) {
        out[batch]     = ld + ld_o;                                      // re plane
        out[B + batch] = 3.14159265358979323846f * (float)(neg + neg_o); // im plane
    }
}

extern "C" void kernel_launch(void* const* d_in, const int* in_sizes, int n_in,
                              void* d_out, int out_size, void* d_ws, size_t ws_size,
                              hipStream_t stream) {
    const int* nocc = (const int*)d_in[0];
    const float* W  = (const float*)d_in[1];
    float* out = (float*)d_out;
    const int B = in_sizes[0] / 128;                 // 65536
    const int blocks = (B + NB - 1) / NB;            // 2048
    backflow_kernel<<<blocks, 512, 0, stream>>>(nocc, W, out, B);
}